// Round 1
// baseline (2694.690 us; speedup 1.0000x reference)
//
#include <hip/hip_runtime.h>
#include <hip/hip_bf16.h>
#include <cstdint>
#include <cstddef>

#define Bq 8192
#define Sq 21
#define Hq 1024
#define Mq (Bq * Sq)   // 172032

typedef __attribute__((ext_vector_type(8))) short short8;
typedef __attribute__((ext_vector_type(4))) float floatx4;

__device__ __forceinline__ short f2b(float x) {
    // RNE float -> bf16 bits (finite inputs only)
    unsigned u = __builtin_bit_cast(unsigned, x);
    unsigned r = (u + 0x7fffu + ((u >> 16) & 1u)) >> 16;
    return (short)r;
}

// ---------------------------------------------------------------------------
// Kernel 0: transpose + convert a [K=1024][N=1024] fp32 matrix into
// [N][K] bf16 (so GEMM B-fragments are contiguous in k).
// ---------------------------------------------------------------------------
__global__ void transpose_cvt(const float* __restrict__ src,
                              unsigned short* __restrict__ dst) {
    __shared__ float tile[32][33];
    const int n0 = blockIdx.x * 32;
    const int k0 = blockIdx.y * 32;
    const int tx = threadIdx.x;   // 0..31
    const int ty = threadIdx.y;   // 0..7
    #pragma unroll
    for (int i = ty; i < 32; i += 8)
        tile[i][tx] = src[(size_t)(k0 + i) * Hq + n0 + tx];
    __syncthreads();
    #pragma unroll
    for (int i = ty; i < 32; i += 8)
        dst[(size_t)(n0 + i) * Hq + k0 + tx] = (unsigned short)f2b(tile[tx][i]);
}

// ---------------------------------------------------------------------------
// Kernel 1: wc = c @ W.  M=8192, N=K=1024. 128x128 tile, BK=64, 4 waves,
// each wave 64x64 via 4x4 grid of 16x16x32 bf16 MFMA.
// ---------------------------------------------------------------------------
__global__ __launch_bounds__(256, 2) void gemm_wc(
    const float* __restrict__ c, const unsigned short* __restrict__ Wtr,
    float* __restrict__ wc)
{
    __shared__ short As[128][72];
    __shared__ short Bs[128][72];

    const int m0 = blockIdx.x * 128;
    const int n0 = blockIdx.y * 128;
    const int t = threadIdx.x;
    const int r = t >> 1;
    const int half = t & 1;

    const float*          arow = c + (size_t)(m0 + r) * Hq + half * 32;
    const unsigned short* brow = Wtr + (size_t)(n0 + r) * Hq + half * 32;

    const int lane = t & 63;
    const int w = t >> 6;
    const int wm = (w & 1) * 64;
    const int wn = (w >> 1) * 64;
    const int l15 = lane & 15;
    const int q = lane >> 4;

    floatx4 acc[4][4] = {};

    for (int k0 = 0; k0 < Hq; k0 += 64) {
        __syncthreads();
        const float4* a4 = reinterpret_cast<const float4*>(arow + k0);
        #pragma unroll
        for (int i = 0; i < 4; ++i) {
            float4 v0 = a4[2 * i], v1 = a4[2 * i + 1];
            short8 p;
            p[0] = f2b(v0.x); p[1] = f2b(v0.y); p[2] = f2b(v0.z); p[3] = f2b(v0.w);
            p[4] = f2b(v1.x); p[5] = f2b(v1.y); p[6] = f2b(v1.z); p[7] = f2b(v1.w);
            *reinterpret_cast<short8*>(&As[r][half * 32 + i * 8]) = p;
        }
        const short8* b8 = reinterpret_cast<const short8*>(brow + k0);
        #pragma unroll
        for (int i = 0; i < 4; ++i)
            *reinterpret_cast<short8*>(&Bs[r][half * 32 + i * 8]) = b8[i];
        __syncthreads();

        #pragma unroll
        for (int kk = 0; kk < 64; kk += 32) {
            short8 af[4], bfr[4];
            #pragma unroll
            for (int i = 0; i < 4; ++i)
                af[i] = *reinterpret_cast<const short8*>(&As[wm + i * 16 + l15][kk + q * 8]);
            #pragma unroll
            for (int j = 0; j < 4; ++j)
                bfr[j] = *reinterpret_cast<const short8*>(&Bs[wn + j * 16 + l15][kk + q * 8]);
            #pragma unroll
            for (int i = 0; i < 4; ++i)
                #pragma unroll
                for (int j = 0; j < 4; ++j)
                    acc[i][j] = __builtin_amdgcn_mfma_f32_16x16x32_bf16(
                        af[i], bfr[j], acc[i][j], 0, 0, 0);
        }
    }

    // store C tile: D[row=(q*4+rr)][col=l15] per fragment
    #pragma unroll
    for (int i = 0; i < 4; ++i) {
        #pragma unroll
        for (int rr = 0; rr < 4; ++rr) {
            const int mm = m0 + wm + i * 16 + q * 4 + rr;
            #pragma unroll
            for (int j = 0; j < 4; ++j) {
                const int nn = n0 + wn + j * 16 + l15;
                wc[(size_t)mm * Hq + nn] = acc[i][j][rr];
            }
        }
    }
}

// ---------------------------------------------------------------------------
// Kernel 2: fused scores GEMM.  Rows m = b*21 + s of allh (layout [S][B][H]),
// B-matrix = V^T (bf16, [n][k]).  Epilogue: tanh(acc + wc[b] + bias[s]) . Wt,
// reduced over this block's 128 n-cols and atomically added into scores[m].
// ---------------------------------------------------------------------------
__global__ __launch_bounds__(256, 2) void gemm_scores(
    const float* __restrict__ allh, const unsigned short* __restrict__ Vt,
    const float* __restrict__ wc, const float* __restrict__ bias,
    const float* __restrict__ Wt, float* __restrict__ scores)
{
    __shared__ short As[128][72];
    __shared__ short Bs[128][72];

    const int m0 = blockIdx.x * 128;
    const int n0 = blockIdx.y * 128;
    const int t = threadIdx.x;
    const int r = t >> 1;
    const int half = t & 1;

    // A row: m -> (b, s); row data is allh[s][b][0..H)
    const int m = m0 + r;
    const int bb = m / 21;
    const int ss = m - bb * 21;
    const float* arow = allh + (size_t)ss * (Bq * Hq) + (size_t)bb * Hq + half * 32;
    const unsigned short* brow = Vt + (size_t)(n0 + r) * Hq + half * 32;

    const int lane = t & 63;
    const int w = t >> 6;
    const int wm = (w & 1) * 64;
    const int wn = (w >> 1) * 64;
    const int l15 = lane & 15;
    const int q = lane >> 4;

    floatx4 acc[4][4] = {};

    for (int k0 = 0; k0 < Hq; k0 += 64) {
        __syncthreads();
        const float4* a4 = reinterpret_cast<const float4*>(arow + k0);
        #pragma unroll
        for (int i = 0; i < 4; ++i) {
            float4 v0 = a4[2 * i], v1 = a4[2 * i + 1];
            short8 p;
            p[0] = f2b(v0.x); p[1] = f2b(v0.y); p[2] = f2b(v0.z); p[3] = f2b(v0.w);
            p[4] = f2b(v1.x); p[5] = f2b(v1.y); p[6] = f2b(v1.z); p[7] = f2b(v1.w);
            *reinterpret_cast<short8*>(&As[r][half * 32 + i * 8]) = p;
        }
        const short8* b8 = reinterpret_cast<const short8*>(brow + k0);
        #pragma unroll
        for (int i = 0; i < 4; ++i)
            *reinterpret_cast<short8*>(&Bs[r][half * 32 + i * 8]) = b8[i];
        __syncthreads();

        #pragma unroll
        for (int kk = 0; kk < 64; kk += 32) {
            short8 af[4], bfr[4];
            #pragma unroll
            for (int i = 0; i < 4; ++i)
                af[i] = *reinterpret_cast<const short8*>(&As[wm + i * 16 + l15][kk + q * 8]);
            #pragma unroll
            for (int j = 0; j < 4; ++j)
                bfr[j] = *reinterpret_cast<const short8*>(&Bs[wn + j * 16 + l15][kk + q * 8]);
            #pragma unroll
            for (int i = 0; i < 4; ++i)
                #pragma unroll
                for (int j = 0; j < 4; ++j)
                    acc[i][j] = __builtin_amdgcn_mfma_f32_16x16x32_bf16(
                        af[i], bfr[j], acc[i][j], 0, 0, 0);
        }
    }

    // Epilogue: e = tanh(vh + wc + bias); partial score = sum_n e*Wt[n]
    float wtv[4];
    #pragma unroll
    for (int j = 0; j < 4; ++j) wtv[j] = Wt[n0 + wn + j * 16 + l15];

    #pragma unroll
    for (int i = 0; i < 4; ++i) {
        #pragma unroll
        for (int rr = 0; rr < 4; ++rr) {
            const int mm = m0 + wm + i * 16 + q * 4 + rr;
            const int b2 = mm / 21;
            const int s2 = mm - b2 * 21;
            const float* wcrow = wc + (size_t)b2 * Hq + n0 + wn;
            const float* birow = bias + (size_t)s2 * Hq + n0 + wn;
            float part = 0.f;
            #pragma unroll
            for (int j = 0; j < 4; ++j) {
                const int nl = j * 16 + l15;
                float e = tanhf(acc[i][j][rr] + wcrow[nl] + birow[nl]);
                part += e * wtv[j];
            }
            // reduce across the 16 lanes (q*16 .. q*16+15) sharing this row
            part += __shfl_xor(part, 1);
            part += __shfl_xor(part, 2);
            part += __shfl_xor(part, 4);
            part += __shfl_xor(part, 8);
            if (l15 == 0) atomicAdd(&scores[mm], part);
        }
    }
}

// ---------------------------------------------------------------------------
// Kernel 3: softmax over S=21 + weighted sum y[b,:] = sum_s alpha_s h[s,b,:]
// ---------------------------------------------------------------------------
__global__ __launch_bounds__(256) void softmax_out(
    const float* __restrict__ scores, const float* __restrict__ allh,
    float* __restrict__ out)
{
    const int b = blockIdx.x;
    const int t = threadIdx.x;

    float sc[Sq];
    float mx = -1e30f;
    #pragma unroll
    for (int s = 0; s < Sq; ++s) {
        sc[s] = scores[(size_t)b * Sq + s];
        mx = fmaxf(mx, sc[s]);
    }
    float sum = 0.f;
    #pragma unroll
    for (int s = 0; s < Sq; ++s) {
        sc[s] = __expf(sc[s] - mx);
        sum += sc[s];
    }
    const float inv = 1.0f / sum;

    #pragma unroll
    for (int h = t; h < Hq; h += 256) {
        float acc = 0.f;
        #pragma unroll
        for (int s = 0; s < Sq; ++s)
            acc += sc[s] * allh[(size_t)s * (Bq * Hq) + (size_t)b * Hq + h];
        out[(size_t)b * Hq + h] = acc * inv;
    }
}

// ---------------------------------------------------------------------------
extern "C" void kernel_launch(void* const* d_in, const int* in_sizes, int n_in,
                              void* d_out, int out_size, void* d_ws, size_t ws_size,
                              hipStream_t stream) {
    const float* c    = (const float*)d_in[0];   // [1, B, H]
    const float* allh = (const float*)d_in[1];   // [S, B, H]
    const float* W    = (const float*)d_in[2];   // [H, H]
    const float* V    = (const float*)d_in[3];   // [H, H]
    const float* bias = (const float*)d_in[4];   // [S, H]
    const float* Wt   = (const float*)d_in[5];   // [H, 1]
    float* out = (float*)d_out;

    char* ws = (char*)d_ws;
    unsigned short* Vt  = (unsigned short*)ws;                       // 2 MB
    unsigned short* Wtr = (unsigned short*)(ws + (2u << 20));        // 2 MB
    float* wc     = (float*)(ws + (4u << 20));                       // 32 MB
    float* scores = (float*)(ws + (4u << 20) + (size_t)Bq * Hq * 4); // 688 KB

    hipMemsetAsync(scores, 0, (size_t)Bq * Sq * sizeof(float), stream);

    transpose_cvt<<<dim3(32, 32), dim3(32, 8), 0, stream>>>(W, Wtr);
    transpose_cvt<<<dim3(32, 32), dim3(32, 8), 0, stream>>>(V, Vt);

    gemm_wc<<<dim3(Bq / 128, Hq / 128), 256, 0, stream>>>(c, Wtr, wc);

    gemm_scores<<<dim3(Mq / 128, Hq / 128), 256, 0, stream>>>(
        allh, Vt, wc, bias, Wt, scores);

    softmax_out<<<Bq, 256, 0, stream>>>(scores, allh, out);
}

// Round 2
// 1847.951 us; speedup vs baseline: 1.4582x; 1.4582x over previous
//
#include <hip/hip_runtime.h>
#include <hip/hip_bf16.h>
#include <cstdint>
#include <cstddef>

#define Bq 8192
#define Sq 21
#define Hq 1024
#define Mq (Bq * Sq)   // 172032

typedef __attribute__((ext_vector_type(8))) short short8;
typedef __attribute__((ext_vector_type(4))) float floatx4;

__device__ __forceinline__ short f2b(float x) {
    // RNE float -> bf16 bits (finite inputs only)
    unsigned u = __builtin_bit_cast(unsigned, x);
    unsigned r = (u + 0x7fffu + ((u >> 16) & 1u)) >> 16;
    return (short)r;
}
__device__ __forceinline__ float b2f(unsigned short b) {
    return __builtin_bit_cast(float, (unsigned)b << 16);
}

// async global->LDS, 16B per lane; LDS dest = wave-uniform base + lane*16
__device__ __forceinline__ void gl_lds16(const void* g, void* l) {
    __builtin_amdgcn_global_load_lds(
        (const __attribute__((address_space(1))) unsigned int*)g,
        (__attribute__((address_space(3))) unsigned int*)l, 16, 0, 0);
}

// ---------------------------------------------------------------------------
// transpose + convert [K][N] fp32 -> [N][K] bf16
// ---------------------------------------------------------------------------
__global__ void transpose_cvt(const float* __restrict__ src,
                              unsigned short* __restrict__ dst) {
    __shared__ float tile[32][33];
    const int n0 = blockIdx.x * 32;
    const int k0 = blockIdx.y * 32;
    const int tx = threadIdx.x;
    const int ty = threadIdx.y;
    #pragma unroll
    for (int i = ty; i < 32; i += 8)
        tile[i][tx] = src[(size_t)(k0 + i) * Hq + n0 + tx];
    __syncthreads();
    #pragma unroll
    for (int i = ty; i < 32; i += 8)
        dst[(size_t)(n0 + i) * Hq + k0 + tx] = (unsigned short)f2b(tile[tx][i]);
}

// ---------------------------------------------------------------------------
// fp32 -> bf16 bulk convert (n8 = elements/8)
// ---------------------------------------------------------------------------
__global__ __launch_bounds__(256) void cvt_bf16(const float* __restrict__ src,
                                                unsigned short* __restrict__ dst,
                                                int n8) {
    int i = blockIdx.x * 256 + threadIdx.x;
    const int stride = gridDim.x * 256;
    for (; i < n8; i += stride) {
        const float4* s4 = reinterpret_cast<const float4*>(src) + (size_t)i * 2;
        float4 a = s4[0], b = s4[1];
        short8 p;
        p[0] = f2b(a.x); p[1] = f2b(a.y); p[2] = f2b(a.z); p[3] = f2b(a.w);
        p[4] = f2b(b.x); p[5] = f2b(b.y); p[6] = f2b(b.z); p[7] = f2b(b.w);
        reinterpret_cast<short8*>(dst)[i] = p;
    }
}

// ---------------------------------------------------------------------------
// m97-style GEMM: 128x128 tile, BK=64, bf16 A/B, global_load_lds staging,
// XOR-swizzled unpadded LDS.  Kernel A: wc = c @ W (stores fp32 wc).
// ---------------------------------------------------------------------------
__global__ __launch_bounds__(256, 3) void gemm_wc2(
    const unsigned short* __restrict__ cb, const unsigned short* __restrict__ Wtr,
    float* __restrict__ wc)
{
    __shared__ unsigned short As[128 * 64];
    __shared__ unsigned short Bs[128 * 64];

    const int n0 = blockIdx.x * 128;
    const int m0 = blockIdx.y * 128;
    const int t = threadIdx.x;
    const int lane = t & 63;
    const int w = t >> 6;

    const int sub = lane >> 3;          // 0..7
    const int k8g = (lane & 7) ^ sub;   // swizzled source k-chunk
    const unsigned short* ap[4];
    const unsigned short* bp[4];
    #pragma unroll
    for (int j = 0; j < 4; ++j) {
        const int r = w * 32 + j * 8 + sub;
        ap[j] = cb + (size_t)(m0 + r) * Hq + k8g * 8;
        bp[j] = Wtr + (size_t)(n0 + r) * Hq + k8g * 8;
    }

    const int wm = (w & 1) * 64;
    const int wn = (w >> 1) * 64;
    const int l15 = lane & 15;
    const int q = lane >> 4;
    const int sw = l15 & 7;

    floatx4 acc[4][4] = {};
    const short8* AsV = (const short8*)As;
    const short8* BsV = (const short8*)Bs;

    for (int k0 = 0; k0 < Hq; k0 += 64) {
        __syncthreads();
        #pragma unroll
        for (int j = 0; j < 4; ++j) {
            gl_lds16(ap[j] + k0, &As[(w * 256 + j * 64) * 8]);
            gl_lds16(bp[j] + k0, &Bs[(w * 256 + j * 64) * 8]);
        }
        __syncthreads();
        #pragma unroll
        for (int kk = 0; kk < 2; ++kk) {
            const int k8 = kk * 4 + q;
            short8 af[4], bfr[4];
            #pragma unroll
            for (int i = 0; i < 4; ++i) {
                af[i]  = AsV[((wm + i * 16 + l15) << 3) | (k8 ^ sw)];
                bfr[i] = BsV[((wn + i * 16 + l15) << 3) | (k8 ^ sw)];
            }
            #pragma unroll
            for (int i = 0; i < 4; ++i)
                #pragma unroll
                for (int j = 0; j < 4; ++j)
                    acc[i][j] = __builtin_amdgcn_mfma_f32_16x16x32_bf16(
                        af[i], bfr[j], acc[i][j], 0, 0, 0);
        }
    }

    #pragma unroll
    for (int i = 0; i < 4; ++i)
        #pragma unroll
        for (int rr = 0; rr < 4; ++rr) {
            const int mm = m0 + wm + i * 16 + q * 4 + rr;
            #pragma unroll
            for (int j = 0; j < 4; ++j) {
                const int nn = n0 + wn + j * 16 + l15;
                wc[(size_t)mm * Hq + nn] = acc[i][j][rr];
            }
        }
}

// ---------------------------------------------------------------------------
// Kernel B: fused scores GEMM over rows m=(b,s) of bf16 allh.
// Epilogue: tanh(acc + wc[b] + bias[s]) . Wt -> atomicAdd scores[m].
// ---------------------------------------------------------------------------
__global__ __launch_bounds__(256, 3) void gemm_scores2(
    const unsigned short* __restrict__ hb, const unsigned short* __restrict__ Vt,
    const float* __restrict__ wc, const float* __restrict__ bias,
    const float* __restrict__ Wt, float* __restrict__ scores)
{
    __shared__ unsigned short As[128 * 64];
    __shared__ unsigned short Bs[128 * 64];

    const int n0 = blockIdx.x * 128;
    const int m0 = blockIdx.y * 128;
    const int t = threadIdx.x;
    const int lane = t & 63;
    const int w = t >> 6;

    const int sub = lane >> 3;
    const int k8g = (lane & 7) ^ sub;
    const unsigned short* ap[4];
    const unsigned short* bp[4];
    #pragma unroll
    for (int j = 0; j < 4; ++j) {
        const int r = w * 32 + j * 8 + sub;
        const int m = m0 + r;
        const int bb = m / 21;
        const int ss = m - bb * 21;
        ap[j] = hb + ((size_t)ss * Bq + bb) * Hq + k8g * 8;
        bp[j] = Vt + (size_t)(n0 + r) * Hq + k8g * 8;
    }

    const int wm = (w & 1) * 64;
    const int wn = (w >> 1) * 64;
    const int l15 = lane & 15;
    const int q = lane >> 4;
    const int sw = l15 & 7;

    floatx4 acc[4][4] = {};
    const short8* AsV = (const short8*)As;
    const short8* BsV = (const short8*)Bs;

    for (int k0 = 0; k0 < Hq; k0 += 64) {
        __syncthreads();
        #pragma unroll
        for (int j = 0; j < 4; ++j) {
            gl_lds16(ap[j] + k0, &As[(w * 256 + j * 64) * 8]);
            gl_lds16(bp[j] + k0, &Bs[(w * 256 + j * 64) * 8]);
        }
        __syncthreads();
        #pragma unroll
        for (int kk = 0; kk < 2; ++kk) {
            const int k8 = kk * 4 + q;
            short8 af[4], bfr[4];
            #pragma unroll
            for (int i = 0; i < 4; ++i) {
                af[i]  = AsV[((wm + i * 16 + l15) << 3) | (k8 ^ sw)];
                bfr[i] = BsV[((wn + i * 16 + l15) << 3) | (k8 ^ sw)];
            }
            #pragma unroll
            for (int i = 0; i < 4; ++i)
                #pragma unroll
                for (int j = 0; j < 4; ++j)
                    acc[i][j] = __builtin_amdgcn_mfma_f32_16x16x32_bf16(
                        af[i], bfr[j], acc[i][j], 0, 0, 0);
        }
    }

    float wtv[4];
    #pragma unroll
    for (int j = 0; j < 4; ++j) wtv[j] = Wt[n0 + wn + j * 16 + l15];

    #pragma unroll
    for (int i = 0; i < 4; ++i) {
        #pragma unroll
        for (int rr = 0; rr < 4; ++rr) {
            const int mm = m0 + wm + i * 16 + q * 4 + rr;
            const int b2 = mm / 21;
            const int s2 = mm - b2 * 21;
            const float* wcrow = wc + (size_t)b2 * Hq + n0 + wn;
            const float* birow = bias + (size_t)s2 * Hq + n0 + wn;
            float part = 0.f;
            #pragma unroll
            for (int j = 0; j < 4; ++j) {
                const int nl = j * 16 + l15;
                float e = tanhf(acc[i][j][rr] + wcrow[nl] + birow[nl]);
                part += e * wtv[j];
            }
            part += __shfl_xor(part, 1);
            part += __shfl_xor(part, 2);
            part += __shfl_xor(part, 4);
            part += __shfl_xor(part, 8);
            if (l15 == 0) atomicAdd(&scores[mm], part);
        }
    }
}

// ---------------------------------------------------------------------------
// softmax over S=21 + y[b,:] = sum_s alpha_s h[s,b,:]  (bf16 h)
// ---------------------------------------------------------------------------
__global__ __launch_bounds__(256) void softmax_out2(
    const float* __restrict__ scores, const unsigned short* __restrict__ hb,
    float* __restrict__ out)
{
    const int b = blockIdx.x;
    const int t = threadIdx.x;

    float sc[Sq];
    float mx = -1e30f;
    #pragma unroll
    for (int s = 0; s < Sq; ++s) {
        sc[s] = scores[(size_t)b * Sq + s];
        mx = fmaxf(mx, sc[s]);
    }
    float sum = 0.f;
    #pragma unroll
    for (int s = 0; s < Sq; ++s) {
        sc[s] = __expf(sc[s] - mx);
        sum += sc[s];
    }
    const float inv = 1.0f / sum;

    const int h = t * 4;
    float a0 = 0.f, a1 = 0.f, a2 = 0.f, a3 = 0.f;
    #pragma unroll
    for (int s = 0; s < Sq; ++s) {
        const unsigned short* p = hb + ((size_t)s * Bq + b) * Hq + h;
        uint2 u = *reinterpret_cast<const uint2*>(p);
        a0 += sc[s] * b2f((unsigned short)(u.x & 0xffffu));
        a1 += sc[s] * b2f((unsigned short)(u.x >> 16));
        a2 += sc[s] * b2f((unsigned short)(u.y & 0xffffu));
        a3 += sc[s] * b2f((unsigned short)(u.y >> 16));
    }
    float4 r;
    r.x = a0 * inv; r.y = a1 * inv; r.z = a2 * inv; r.w = a3 * inv;
    *reinterpret_cast<float4*>(out + (size_t)b * Hq + h) = r;
}

// ===========================================================================
// Fallback path (round-1, needs only ~38 MB ws) — used if ws_size too small.
// ===========================================================================
__global__ __launch_bounds__(256, 2) void gemm_wc_fb(
    const float* __restrict__ c, const unsigned short* __restrict__ Wtr,
    float* __restrict__ wc)
{
    __shared__ short As[128][72];
    __shared__ short Bs[128][72];
    const int m0 = blockIdx.x * 128;
    const int n0 = blockIdx.y * 128;
    const int t = threadIdx.x;
    const int r = t >> 1;
    const int half = t & 1;
    const float*          arow = c + (size_t)(m0 + r) * Hq + half * 32;
    const unsigned short* brow = Wtr + (size_t)(n0 + r) * Hq + half * 32;
    const int lane = t & 63;
    const int w = t >> 6;
    const int wm = (w & 1) * 64;
    const int wn = (w >> 1) * 64;
    const int l15 = lane & 15;
    const int q = lane >> 4;
    floatx4 acc[4][4] = {};
    for (int k0 = 0; k0 < Hq; k0 += 64) {
        __syncthreads();
        const float4* a4 = reinterpret_cast<const float4*>(arow + k0);
        #pragma unroll
        for (int i = 0; i < 4; ++i) {
            float4 v0 = a4[2 * i], v1 = a4[2 * i + 1];
            short8 p;
            p[0] = f2b(v0.x); p[1] = f2b(v0.y); p[2] = f2b(v0.z); p[3] = f2b(v0.w);
            p[4] = f2b(v1.x); p[5] = f2b(v1.y); p[6] = f2b(v1.z); p[7] = f2b(v1.w);
            *reinterpret_cast<short8*>(&As[r][half * 32 + i * 8]) = p;
        }
        const short8* b8 = reinterpret_cast<const short8*>(brow + k0);
        #pragma unroll
        for (int i = 0; i < 4; ++i)
            *reinterpret_cast<short8*>(&Bs[r][half * 32 + i * 8]) = b8[i];
        __syncthreads();
        #pragma unroll
        for (int kk = 0; kk < 64; kk += 32) {
            short8 af[4], bfr[4];
            #pragma unroll
            for (int i = 0; i < 4; ++i)
                af[i] = *reinterpret_cast<const short8*>(&As[wm + i * 16 + l15][kk + q * 8]);
            #pragma unroll
            for (int j = 0; j < 4; ++j)
                bfr[j] = *reinterpret_cast<const short8*>(&Bs[wn + j * 16 + l15][kk + q * 8]);
            #pragma unroll
            for (int i = 0; i < 4; ++i)
                #pragma unroll
                for (int j = 0; j < 4; ++j)
                    acc[i][j] = __builtin_amdgcn_mfma_f32_16x16x32_bf16(
                        af[i], bfr[j], acc[i][j], 0, 0, 0);
        }
    }
    #pragma unroll
    for (int i = 0; i < 4; ++i)
        #pragma unroll
        for (int rr = 0; rr < 4; ++rr) {
            const int mm = m0 + wm + i * 16 + q * 4 + rr;
            #pragma unroll
            for (int j = 0; j < 4; ++j)
                wc[(size_t)mm * Hq + n0 + wn + j * 16 + l15] = acc[i][j][rr];
        }
}

__global__ __launch_bounds__(256, 2) void gemm_scores_fb(
    const float* __restrict__ allh, const unsigned short* __restrict__ Vt,
    const float* __restrict__ wc, const float* __restrict__ bias,
    const float* __restrict__ Wt, float* __restrict__ scores)
{
    __shared__ short As[128][72];
    __shared__ short Bs[128][72];
    const int m0 = blockIdx.x * 128;
    const int n0 = blockIdx.y * 128;
    const int t = threadIdx.x;
    const int r = t >> 1;
    const int half = t & 1;
    const int m = m0 + r;
    const int bb = m / 21;
    const int ss = m - bb * 21;
    const float* arow = allh + (size_t)ss * (Bq * Hq) + (size_t)bb * Hq + half * 32;
    const unsigned short* brow = Vt + (size_t)(n0 + r) * Hq + half * 32;
    const int lane = t & 63;
    const int w = t >> 6;
    const int wm = (w & 1) * 64;
    const int wn = (w >> 1) * 64;
    const int l15 = lane & 15;
    const int q = lane >> 4;
    floatx4 acc[4][4] = {};
    for (int k0 = 0; k0 < Hq; k0 += 64) {
        __syncthreads();
        const float4* a4 = reinterpret_cast<const float4*>(arow + k0);
        #pragma unroll
        for (int i = 0; i < 4; ++i) {
            float4 v0 = a4[2 * i], v1 = a4[2 * i + 1];
            short8 p;
            p[0] = f2b(v0.x); p[1] = f2b(v0.y); p[2] = f2b(v0.z); p[3] = f2b(v0.w);
            p[4] = f2b(v1.x); p[5] = f2b(v1.y); p[6] = f2b(v1.z); p[7] = f2b(v1.w);
            *reinterpret_cast<short8*>(&As[r][half * 32 + i * 8]) = p;
        }
        const short8* b8 = reinterpret_cast<const short8*>(brow + k0);
        #pragma unroll
        for (int i = 0; i < 4; ++i)
            *reinterpret_cast<short8*>(&Bs[r][half * 32 + i * 8]) = b8[i];
        __syncthreads();
        #pragma unroll
        for (int kk = 0; kk < 64; kk += 32) {
            short8 af[4], bfr[4];
            #pragma unroll
            for (int i = 0; i < 4; ++i)
                af[i] = *reinterpret_cast<const short8*>(&As[wm + i * 16 + l15][kk + q * 8]);
            #pragma unroll
            for (int j = 0; j < 4; ++j)
                bfr[j] = *reinterpret_cast<const short8*>(&Bs[wn + j * 16 + l15][kk + q * 8]);
            #pragma unroll
            for (int i = 0; i < 4; ++i)
                #pragma unroll
                for (int j = 0; j < 4; ++j)
                    acc[i][j] = __builtin_amdgcn_mfma_f32_16x16x32_bf16(
                        af[i], bfr[j], acc[i][j], 0, 0, 0);
        }
    }
    float wtv[4];
    #pragma unroll
    for (int j = 0; j < 4; ++j) wtv[j] = Wt[n0 + wn + j * 16 + l15];
    #pragma unroll
    for (int i = 0; i < 4; ++i)
        #pragma unroll
        for (int rr = 0; rr < 4; ++rr) {
            const int mm = m0 + wm + i * 16 + q * 4 + rr;
            const int b2 = mm / 21;
            const int s2 = mm - b2 * 21;
            const float* wcrow = wc + (size_t)b2 * Hq + n0 + wn;
            const float* birow = bias + (size_t)s2 * Hq + n0 + wn;
            float part = 0.f;
            #pragma unroll
            for (int j = 0; j < 4; ++j) {
                const int nl = j * 16 + l15;
                float e = tanhf(acc[i][j][rr] + wcrow[nl] + birow[nl]);
                part += e * wtv[j];
            }
            part += __shfl_xor(part, 1);
            part += __shfl_xor(part, 2);
            part += __shfl_xor(part, 4);
            part += __shfl_xor(part, 8);
            if (l15 == 0) atomicAdd(&scores[mm], part);
        }
}

__global__ __launch_bounds__(256) void softmax_out_fb(
    const float* __restrict__ scores, const float* __restrict__ allh,
    float* __restrict__ out)
{
    const int b = blockIdx.x;
    const int t = threadIdx.x;
    float sc[Sq];
    float mx = -1e30f;
    #pragma unroll
    for (int s = 0; s < Sq; ++s) {
        sc[s] = scores[(size_t)b * Sq + s];
        mx = fmaxf(mx, sc[s]);
    }
    float sum = 0.f;
    #pragma unroll
    for (int s = 0; s < Sq; ++s) {
        sc[s] = __expf(sc[s] - mx);
        sum += sc[s];
    }
    const float inv = 1.0f / sum;
    for (int h = t; h < Hq; h += 256) {
        float acc = 0.f;
        #pragma unroll
        for (int s = 0; s < Sq; ++s)
            acc += sc[s] * allh[(size_t)s * (Bq * Hq) + (size_t)b * Hq + h];
        out[(size_t)b * Hq + h] = acc * inv;
    }
}

// ---------------------------------------------------------------------------
extern "C" void kernel_launch(void* const* d_in, const int* in_sizes, int n_in,
                              void* d_out, int out_size, void* d_ws, size_t ws_size,
                              hipStream_t stream) {
    const float* c    = (const float*)d_in[0];
    const float* allh = (const float*)d_in[1];
    const float* W    = (const float*)d_in[2];
    const float* V    = (const float*)d_in[3];
    const float* bias = (const float*)d_in[4];
    const float* Wt   = (const float*)d_in[5];
    float* out = (float*)d_out;
    char* ws = (char*)d_ws;

    const size_t NEED = 411041792ULL;  // ~392 MiB fast-path scratch

    if (ws_size >= NEED) {
        unsigned short* Vt  = (unsigned short*)ws;                 // 2 MB
        unsigned short* Wtr = (unsigned short*)(ws + 2097152);     // 2 MB
        float* wc           = (float*)(ws + 4194304);              // 32 MB
        float* scores       = (float*)(ws + 37748736);             // 688 KB
        unsigned short* cb  = (unsigned short*)(ws + 41943040);    // 16 MB
        unsigned short* hb  = (unsigned short*)(ws + 58720256);    // 336 MB

        hipMemsetAsync(scores, 0, (size_t)Bq * Sq * sizeof(float), stream);
        transpose_cvt<<<dim3(32, 32), dim3(32, 8), 0, stream>>>(W, Wtr);
        transpose_cvt<<<dim3(32, 32), dim3(32, 8), 0, stream>>>(V, Vt);
        cvt_bf16<<<1024, 256, 0, stream>>>(c, cb, Bq * Hq / 8);
        cvt_bf16<<<4096, 256, 0, stream>>>(allh, hb, Sq * (Bq / 8) * Hq);

        gemm_wc2<<<dim3(Hq / 128, Bq / 128), 256, 0, stream>>>(cb, Wtr, wc);
        gemm_scores2<<<dim3(Hq / 128, Mq / 128), 256, 0, stream>>>(
            hb, Vt, wc, bias, Wt, scores);
        softmax_out2<<<Bq, 256, 0, stream>>>(scores, hb, out);
    } else {
        unsigned short* Vt  = (unsigned short*)ws;
        unsigned short* Wtr = (unsigned short*)(ws + (2u << 20));
        float* wc     = (float*)(ws + (4u << 20));
        float* scores = (float*)(ws + (4u << 20) + (size_t)Bq * Hq * 4);

        hipMemsetAsync(scores, 0, (size_t)Bq * Sq * sizeof(float), stream);
        transpose_cvt<<<dim3(32, 32), dim3(32, 8), 0, stream>>>(W, Wtr);
        transpose_cvt<<<dim3(32, 32), dim3(32, 8), 0, stream>>>(V, Vt);
        gemm_wc_fb<<<dim3(Bq / 128, Hq / 128), 256, 0, stream>>>(c, Wtr, wc);
        gemm_scores_fb<<<dim3(Mq / 128, Hq / 128), 256, 0, stream>>>(
            allh, Vt, wc, bias, Wt, scores);
        softmax_out_fb<<<Bq, 256, 0, stream>>>(scores, allh, out);
    }
}